// Round 5
// baseline (266.453 us; speedup 1.0000x reference)
//
#include <hip/hip_runtime.h>

// BackgroundNoiseLayer, fused plan (round 5):
//   out[t, n*5+r] = sum_k spikes[t,k] * W[k, n*5+r],
//   W[k, c] = scatter-add over edges e (cols[e]=k, rows[e]=n) of weights[e]*tau[e,r]
//
// memset: zero bin counters (graph-legal hipMemsetAsync)
// K1: bucket edges by neuron-range (bin = row/8), record = {key, w*tau[0..4]};
//     first 128 blocks also build the zero-padded bf16 spike table spb[256][128]
// K2: per block (8 neurons = 40 cols): preload records -> zero f32 LDS slice ->
//     LDS atomic scatter -> one bf16 hi/lo convert into transposed XOR-swizzled
//     LDS -> MFMA GEMM (A=W-limbs from LDS, B=spikes) -> float4 nt stores.
//     W never exists in global memory.

#define N_NEURONS 50000
#define N_BKG     100
#define N_SYN     5
#define N_EDGES   500000
#define SEQ_T     250
#define NCOL      (N_NEURONS * N_SYN)   // 250000
#define RPB       8                     // neurons per bin/block
#define NBINS     (N_NEURONS / RPB)     // 6250
#define CAP       256                   // record cap per bin (mean 80, +19.7 sigma)
#define REC_U32   8                     // 32 B record stride
#define KPAD      128                   // K padded 100 -> 128 (zeros)
#define CPAD      41                    // f32 slice leading dim (40 cols + 1)
#define BCOLS     40                    // valid output cols per block
#define CPADC     48                    // padded cols (3 m-tiles)
#define LO_OFF    12288                 // 48*128*2 B = hi-limb region size

// d_ws layout
#define WS_COUNT_OFF 0                  // NBINS u32 = 25000 B
#define WS_SPB_OFF   32768              // 256*128 bf16 = 64 KB
#define WS_REC_OFF   131072             // NBINS*CAP*32 B = 51.2 MB

typedef __attribute__((ext_vector_type(8))) short bf16x8;
typedef __attribute__((ext_vector_type(4))) float f32x4;

__device__ inline unsigned short bf16_rne(float f) {
    unsigned u = __builtin_bit_cast(unsigned, f);
    u += 0x7FFFu + ((u >> 16) & 1u);
    return (unsigned short)(u >> 16);
}

// K1: bucket-append edges; first 32768 gids also build spb.
__global__ __launch_bounds__(256) void bucket_kernel(
        const float* __restrict__ weights,
        const float* __restrict__ tau,
        const int*   __restrict__ rows,
        const int*   __restrict__ cols,
        const float* __restrict__ spikes,
        unsigned* __restrict__ count,
        unsigned* __restrict__ rec,
        unsigned short* __restrict__ spb) {
    int gid = blockIdx.x * 256 + threadIdx.x;
    if (gid < 256 * KPAD) {                      // spb[t][k], 256 x 128
        int t = gid >> 7, k = gid & 127;
        unsigned short v = 0;
        if (t < SEQ_T && k < N_BKG) {
            float s = spikes[t * N_BKG + k];     // 0.0f / 1.0f -> bf16 exact
            v = (unsigned short)(__builtin_bit_cast(unsigned, s) >> 16);
        }
        spb[gid] = v;
    }
    if (gid >= N_EDGES) return;
    int row = rows[gid];
    int col = cols[gid];
    float w = weights[gid];
    const float* tp = tau + (size_t)gid * N_SYN;
    int bin = row >> 3;                          // row / RPB
    unsigned slot = atomicAdd(&count[bin], 1u);
    if (slot >= CAP) return;                     // statistically impossible
    unsigned* rp = rec + ((size_t)bin * CAP + slot) * REC_U32;
    uint4 r0;
    uint2 r1;
    r0.x = ((unsigned)col << 3) | (unsigned)(row & 7);
    r0.y = __builtin_bit_cast(unsigned, w * tp[0]);
    r0.z = __builtin_bit_cast(unsigned, w * tp[1]);
    r0.w = __builtin_bit_cast(unsigned, w * tp[2]);
    r1.x = __builtin_bit_cast(unsigned, w * tp[3]);
    r1.y = __builtin_bit_cast(unsigned, w * tp[4]);
    *(uint4*)(rp)     = r0;
    *(uint2*)(rp + 4) = r1;
}

// K2: fused scatter + convert + MFMA GEMM. 6250 blocks x 256 (4 waves).
// Block b: neurons [8b, 8b+8) -> output cols [40b, 40b+40).
// Swapped operands: A = W-limb frag (row = c = l&15 within m-tile),
// B = spike frag (col = t = l&15 within n-tile), k = (l>>4)*8+i.
// D: col = t = l&15, row = c = (l>>4)*4+reg -> float4 stores along c.
__global__ __launch_bounds__(256, 4) void fused_kernel(
        const unsigned* __restrict__ count,
        const unsigned* __restrict__ rec,
        const unsigned short* __restrict__ spb,
        float* __restrict__ out) {
    __shared__ __align__(16) char lds[2 * LO_OFF];   // 24576 B union
    float* slice = (float*)lds;                      // f32 [100][41] = 16400 B

    const int tid = threadIdx.x;
    const int b   = blockIdx.x;

    // ---- preload this block's record (1 per thread; overlaps zeroing) ----
    unsigned cnt = count[b];
    if (cnt > CAP) cnt = CAP;
    uint4 r0;
    uint2 r1;
    bool have = (unsigned)tid < cnt;
    if (have) {
        const unsigned* rp = rec + ((size_t)b * CAP + tid) * REC_U32;
        r0 = *(const uint4*)(rp);
        r1 = *(const uint2*)(rp + 4);
    }

    // ---- zero f32 slice (4100 floats = 1025 float4) ----
    {
        float4* s4 = (float4*)slice;
        float4 z = make_float4(0.f, 0.f, 0.f, 0.f);
#pragma unroll
        for (int j = 0; j < 4; ++j) s4[tid + j * 256] = z;
        if (tid == 0) s4[1024] = z;
    }
    __syncthreads();

    // ---- LDS atomic scatter ----
    if (have) {
        int k    = (int)(r0.x >> 3);
        int noff = (int)(r0.x & 7u);
        float* base = &slice[k * CPAD + noff * N_SYN];
        atomicAdd(base + 0, __builtin_bit_cast(float, r0.y));
        atomicAdd(base + 1, __builtin_bit_cast(float, r0.z));
        atomicAdd(base + 2, __builtin_bit_cast(float, r0.w));
        atomicAdd(base + 3, __builtin_bit_cast(float, r1.x));
        atomicAdd(base + 4, __builtin_bit_cast(float, r1.y));
    }
    __syncthreads();

    // ---- convert once to bf16 hi/lo, transposed [c][k], XOR-swizzled ----
    // 768 chunks of (c, 8 k); reg-staged across barrier, written in-place.
    bf16x8 hi[3], lo[3];
    unsigned bo[3];
#pragma unroll
    for (int j = 0; j < 3; ++j) {
        int m  = tid + j * 256;                  // 0..767
        int c  = m % CPADC;
        int kb = m / CPADC;                      // 0..15
#pragma unroll
        for (int i = 0; i < 8; ++i) {
            int k = kb * 8 + i;
            float v = (c < BCOLS && k < N_BKG) ? slice[k * CPAD + c] : 0.f;
            unsigned short h = bf16_rne(v);
            float hf = __builtin_bit_cast(float, (unsigned)h << 16);
            hi[j][i] = (short)h;
            lo[j][i] = (short)bf16_rne(v - hf);
        }
        bo[j] = (unsigned)((c * 256 + kb * 16) ^ ((c & 7) << 4));
    }
    __syncthreads();
#pragma unroll
    for (int j = 0; j < 3; ++j) {
        *(bf16x8*)(lds + bo[j])          = hi[j];
        *(bf16x8*)(lds + LO_OFF + bo[j]) = lo[j];
    }
    __syncthreads();

    // ---- MFMA GEMM (A = W limbs, B = spikes) ----
    const int l  = tid & 63;
    const int wv = tid >> 6;
    const int lc = l & 15;
    const int lq = l >> 4;

    f32x4 acc[3][4];
#pragma unroll
    for (int m = 0; m < 3; ++m)
#pragma unroll
        for (int n = 0; n < 4; ++n)
            acc[m][n] = (f32x4){0.f, 0.f, 0.f, 0.f};

#pragma unroll
    for (int kk = 0; kk < 4; ++kk) {
        bf16x8 bs[4];
#pragma unroll
        for (int n = 0; n < 4; ++n) {
            int t = (wv * 4 + n) * 16 + lc;              // < 256, pad rows 0
            bs[n] = *(const bf16x8*)(spb + (size_t)t * KPAD + kk * 32 + lq * 8);
        }
#pragma unroll
        for (int m = 0; m < 3; ++m) {
            int c = m * 16 + lc;
            unsigned bor = (unsigned)((c * 256 + kk * 64 + lq * 16) ^ ((c & 7) << 4));
            bf16x8 ah = *(const bf16x8*)(lds + bor);
            bf16x8 al = *(const bf16x8*)(lds + LO_OFF + bor);
#pragma unroll
            for (int n = 0; n < 4; ++n) {
                acc[m][n] = __builtin_amdgcn_mfma_f32_16x16x32_bf16(
                                ah, bs[n], acc[m][n], 0, 0, 0);
                acc[m][n] = __builtin_amdgcn_mfma_f32_16x16x32_bf16(
                                al, bs[n], acc[m][n], 0, 0, 0);
            }
        }
    }

    // ---- stores: thread holds 4 consecutive c -> float4 nt stores ----
    const int cb = b * BCOLS;
#pragma unroll
    for (int m = 0; m < 3; ++m) {
        int c = cb + m * 16 + lq * 4;
        bool cok = (m < 2) | (lq < 2);           // cols 40..47 are pad
#pragma unroll
        for (int n = 0; n < 4; ++n) {
            int t = (wv * 4 + n) * 16 + lc;
            if (cok && t < SEQ_T)
                __builtin_nontemporal_store(
                    acc[m][n], (f32x4*)(out + (size_t)t * NCOL + c));
        }
    }
}

extern "C" void kernel_launch(void* const* d_in, const int* in_sizes, int n_in,
                              void* d_out, int out_size, void* d_ws, size_t ws_size,
                              hipStream_t stream) {
    const float* weights = (const float*)d_in[0];
    const float* tau     = (const float*)d_in[1];
    const float* spikes  = (const float*)d_in[2];
    const int*   rows    = (const int*)d_in[3];
    const int*   cols    = (const int*)d_in[4];
    float* out = (float*)d_out;

    char* ws = (char*)d_ws;
    unsigned*       count = (unsigned*)(ws + WS_COUNT_OFF);
    unsigned short* spb   = (unsigned short*)(ws + WS_SPB_OFF);
    unsigned*       rec   = (unsigned*)(ws + WS_REC_OFF);

    hipMemsetAsync(count, 0, NBINS * sizeof(unsigned), stream);

    int eblocks = (N_EDGES + 255) / 256;         // 1954 (covers spb's 128 too)
    bucket_kernel<<<eblocks, 256, 0, stream>>>(weights, tau, rows, cols, spikes,
                                               count, rec, spb);

    fused_kernel<<<NBINS, 256, 0, stream>>>(count, rec, spb, out);
}

// Round 6
// 123.441 us; speedup vs baseline: 2.1585x; 2.1585x over previous
//
#include <hip/hip_runtime.h>

// BackgroundNoiseLayer, fused plan (round 6):
//   out[t, n*5+r] = sum_k spikes[t,k] * W[k, n*5+r],
//   W[k, c] = scatter-add over edges e (cols[e]=k, rows[e]=n) of weights[e]*tau[e,r]
//
// memset: zero bin counters (graph-legal hipMemsetAsync)
// K1: bucket edges by neuron-range (bin = row/16); record = 16 B
//     {key, 5 x bf16 w*tau}; first 128 blocks also build bf16 spike table
//     spb[256][128] (zero-padded).
// K2: per block (16 neurons = 80 cols): preload records -> zero f32 LDS slice
//     -> LDS atomic scatter -> ONE bf16 convert into transposed XOR-swizzled
//     LDS -> MFMA GEMM (A = W bf16 from LDS, B = spikes) -> float4 stores.
//     Single bf16 limb: W rel err 2^-9, ~2.5 active edges per output ->
//     max out err ~5e-3 << 0.1925 threshold. W never exists in global memory.

#define N_NEURONS 50000
#define N_BKG     100
#define N_SYN     5
#define N_EDGES   500000
#define SEQ_T     250
#define NCOL      (N_NEURONS * N_SYN)   // 250000
#define RPB       16                    // neurons per bin/block
#define NBINS     (N_NEURONS / RPB)     // 3125
#define CAP       512                   // record cap per bin (mean 160, +28 sigma)
#define REC_U32   4                     // 16 B record
#define KPAD      128                   // K padded 100 -> 128 (zeros)
#define CPAD      80                    // f32 slice leading dim
#define BCOLS     80                    // output cols per block (320 B, line-aligned)
#define LDS_BYTES 32000                 // f32 slice 100*80*4; bf16 area 80*128*2=20480

// d_ws layout
#define WS_COUNT_OFF 0                  // NBINS u32 = 12.5 KB
#define WS_SPB_OFF   32768              // 256*128 bf16 = 64 KB
#define WS_REC_OFF   131072             // NBINS*CAP*16 B = 25.6 MB

typedef __attribute__((ext_vector_type(8))) short bf16x8;
typedef __attribute__((ext_vector_type(4))) float f32x4;

__device__ inline unsigned short bf16_rne(float f) {
    unsigned u = __builtin_bit_cast(unsigned, f);
    u += 0x7FFFu + ((u >> 16) & 1u);
    return (unsigned short)(u >> 16);
}
__device__ inline float bf16_up(unsigned hw) {
    return __builtin_bit_cast(float, hw << 16);
}

// K1: bucket-append edges (16 B records); first 32768 gids also build spb.
__global__ __launch_bounds__(256) void bucket_kernel(
        const float* __restrict__ weights,
        const float* __restrict__ tau,
        const int*   __restrict__ rows,
        const int*   __restrict__ cols,
        const float* __restrict__ spikes,
        unsigned* __restrict__ count,
        uint4* __restrict__ rec,
        unsigned short* __restrict__ spb) {
    int gid = blockIdx.x * 256 + threadIdx.x;
    if (gid < 256 * KPAD) {                      // spb[t][k], 256 x 128
        int t = gid >> 7, k = gid & 127;
        unsigned short v = 0;
        if (t < SEQ_T && k < N_BKG) {
            float s = spikes[t * N_BKG + k];     // 0.0f / 1.0f -> bf16 exact
            v = bf16_rne(s);
        }
        spb[gid] = v;
    }
    if (gid >= N_EDGES) return;
    int row = rows[gid];
    int col = cols[gid];
    float w = weights[gid];
    const float* tp = tau + (size_t)gid * N_SYN;
    int bin = row >> 4;                          // row / RPB
    unsigned slot = atomicAdd(&count[bin], 1u);
    if (slot >= CAP) return;                     // statistically impossible
    uint4 r;
    r.x = ((unsigned)col << 4) | (unsigned)(row & 15);
    r.y = (unsigned)bf16_rne(w * tp[0]) | ((unsigned)bf16_rne(w * tp[1]) << 16);
    r.z = (unsigned)bf16_rne(w * tp[2]) | ((unsigned)bf16_rne(w * tp[3]) << 16);
    r.w = (unsigned)bf16_rne(w * tp[4]);
    rec[(size_t)bin * CAP + slot] = r;
}

// K2: fused scatter + convert + MFMA GEMM. 3125 blocks x 256 (4 waves).
// Block b: neurons [16b,16b+16) -> output cols [80b, 80b+80).
// Swapped operands: A = W bf16 frag (M = c: row = l&15 within m-tile),
// B = spike frag (N = t: col = l&15 within n-tile), k = (l>>4)*8+i.
// D: col = t = l&15, row = c = (l>>4)*4+reg -> float4 stores along c.
__global__ __launch_bounds__(256, 4) void fused_kernel(
        const unsigned* __restrict__ count,
        const uint4* __restrict__ rec,
        const unsigned short* __restrict__ spb,
        float* __restrict__ out) {
    __shared__ __align__(16) char lds[LDS_BYTES];
    float* slice = (float*)lds;                  // f32 [100][80]

    const int tid = threadIdx.x;
    const int b   = blockIdx.x;

    // ---- preload this block's records (2/thread max; overlaps zeroing) ----
    unsigned cnt = count[b];
    if (cnt > CAP) cnt = CAP;
    uint4 ra, rb;
    bool havea = (unsigned)tid < cnt;
    bool haveb = (unsigned)(tid + 256) < cnt;
    if (havea) ra = rec[(size_t)b * CAP + tid];
    if (haveb) rb = rec[(size_t)b * CAP + tid + 256];

    // ---- zero f32 slice (8000 floats = 2000 float4) ----
    {
        float4* s4 = (float4*)slice;
        float4 z = make_float4(0.f, 0.f, 0.f, 0.f);
#pragma unroll
        for (int j = 0; j < 8; ++j) {
            int i = tid + j * 256;
            if (i < 2000) s4[i] = z;
        }
    }
    __syncthreads();

    // ---- LDS atomic scatter (bf16 values widened to f32) ----
    if (havea) {
        float* base = &slice[(ra.x >> 4) * CPAD + (ra.x & 15u) * N_SYN];
        atomicAdd(base + 0, bf16_up(ra.y & 0xFFFFu));
        atomicAdd(base + 1, bf16_up(ra.y >> 16));
        atomicAdd(base + 2, bf16_up(ra.z & 0xFFFFu));
        atomicAdd(base + 3, bf16_up(ra.z >> 16));
        atomicAdd(base + 4, bf16_up(ra.w & 0xFFFFu));
    }
    if (haveb) {
        float* base = &slice[(rb.x >> 4) * CPAD + (rb.x & 15u) * N_SYN];
        atomicAdd(base + 0, bf16_up(rb.y & 0xFFFFu));
        atomicAdd(base + 1, bf16_up(rb.y >> 16));
        atomicAdd(base + 2, bf16_up(rb.z & 0xFFFFu));
        atomicAdd(base + 3, bf16_up(rb.z >> 16));
        atomicAdd(base + 4, bf16_up(rb.w & 0xFFFFu));
    }
    __syncthreads();

    // ---- convert once to bf16, transposed [c][k], XOR-swizzled ----
    // 1280 chunks of (c, 8 consecutive k); reg-staged across the barrier.
    bf16x8 hi[5];
    unsigned bo[5];
#pragma unroll
    for (int j = 0; j < 5; ++j) {
        int m  = tid + j * 256;                  // 0..1279
        int c  = m % BCOLS;
        int kb = m / BCOLS;                      // 0..15
#pragma unroll
        for (int i = 0; i < 8; ++i) {
            int k = kb * 8 + i;
            float v = (k < N_BKG) ? slice[k * CPAD + c] : 0.f;
            hi[j][i] = (short)bf16_rne(v);
        }
        bo[j] = (unsigned)((c * 256 + kb * 16) ^ ((c & 7) << 4));
    }
    __syncthreads();
#pragma unroll
    for (int j = 0; j < 5; ++j)
        *(bf16x8*)(lds + bo[j]) = hi[j];
    __syncthreads();

    // ---- MFMA GEMM (A = W bf16, B = spikes) ----
    const int l  = tid & 63;
    const int wv = tid >> 6;
    const int lc = l & 15;
    const int lq = l >> 4;

    f32x4 acc[5][4];
#pragma unroll
    for (int m = 0; m < 5; ++m)
#pragma unroll
        for (int n = 0; n < 4; ++n)
            acc[m][n] = (f32x4){0.f, 0.f, 0.f, 0.f};

#pragma unroll
    for (int kk = 0; kk < 4; ++kk) {
        bf16x8 bs[4];
#pragma unroll
        for (int n = 0; n < 4; ++n) {
            int t = (wv * 4 + n) * 16 + lc;              // < 256, pad rows 0
            bs[n] = *(const bf16x8*)(spb + (size_t)t * KPAD + kk * 32 + lq * 8);
        }
#pragma unroll
        for (int m = 0; m < 5; ++m) {
            int c = m * 16 + lc;
            unsigned bor = (unsigned)((c * 256 + kk * 64 + lq * 16) ^ ((c & 7) << 4));
            bf16x8 ah = *(const bf16x8*)(lds + bor);
#pragma unroll
            for (int n = 0; n < 4; ++n)
                acc[m][n] = __builtin_amdgcn_mfma_f32_16x16x32_bf16(
                                ah, bs[n], acc[m][n], 0, 0, 0);
        }
    }

    // ---- stores: thread holds 4 consecutive c -> float4 stores ----
    const int cb = b * BCOLS;
#pragma unroll
    for (int m = 0; m < 5; ++m) {
        int c = cb + m * 16 + lq * 4;
#pragma unroll
        for (int n = 0; n < 4; ++n) {
            int t = (wv * 4 + n) * 16 + lc;
            if (t < SEQ_T)
                *(f32x4*)(out + (size_t)t * NCOL + c) = acc[m][n];
        }
    }
}

extern "C" void kernel_launch(void* const* d_in, const int* in_sizes, int n_in,
                              void* d_out, int out_size, void* d_ws, size_t ws_size,
                              hipStream_t stream) {
    const float* weights = (const float*)d_in[0];
    const float* tau     = (const float*)d_in[1];
    const float* spikes  = (const float*)d_in[2];
    const int*   rows    = (const int*)d_in[3];
    const int*   cols    = (const int*)d_in[4];
    float* out = (float*)d_out;

    char* ws = (char*)d_ws;
    unsigned*       count = (unsigned*)(ws + WS_COUNT_OFF);
    unsigned short* spb   = (unsigned short*)(ws + WS_SPB_OFF);
    uint4*          rec   = (uint4*)(ws + WS_REC_OFF);

    hipMemsetAsync(count, 0, NBINS * sizeof(unsigned), stream);

    int eblocks = (N_EDGES + 255) / 256;         // 1954 (covers spb's 128 too)
    bucket_kernel<<<eblocks, 256, 0, stream>>>(weights, tau, rows, cols, spikes,
                                               count, rec, spb);

    fused_kernel<<<NBINS, 256, 0, stream>>>(count, rec, spb, out);
}